// Round 5
// baseline (239.761 us; speedup 1.0000x reference)
//
#include <hip/hip_runtime.h>
#include <math.h>

#define K 32
#define F 128
#define H 256
#define TAB 4096
#define QB 8
#define BMAX 16
#define RCUT2 100.0f
#define KBINS 64
#define BINCAP 2560
#define BCAP 128
#define FP 132   // padded LDS row stride (16B-aligned, bank-skewed)
#define FR 16    // rows per block in row-broadcast GEMMs

__device__ __forceinline__ float ssp(float x) {
    // jax.nn.softplus(x) - log(2)
    return fmaxf(x, 0.0f) + log1pf(expf(-fabsf(x))) - 0.69314718055994531f;
}

// d2 with pinned fma contraction so pass A and pass B agree bit-exactly
__device__ __forceinline__ float d2f4(float4 p, float qx, float qy, float qz) {
    float dx = qx - p.x;
    float dy = qy - p.y;
    float dz = qz - p.z;
    return fmaf(dz, dz, fmaf(dy, dy, dx * dx));
}

// ---------------- prep: seg boundaries + pos padding + gaussian-smearing grid ----------------
// block 0: ctx_start binary search; blocks 1..padB: posc->float4; rest: GS[t][j]
__global__ __launch_bounds__(256) void prep_kernel(const int* __restrict__ bc, int Nc,
                                                   int* __restrict__ ctx_start,
                                                   const float* __restrict__ posc,
                                                   float4* __restrict__ posc4,
                                                   float* __restrict__ gs, int padB) {
    int blk = blockIdx.x;
    int tid = threadIdx.x;
    if (blk == 0) {
        if (tid <= BMAX) {
            int b = tid;
            int lo = 0, hi = Nc;
            while (lo < hi) {
                int mid = (lo + hi) >> 1;
                if (bc[mid] < b) lo = mid + 1; else hi = mid;
            }
            ctx_start[b] = lo;
        }
    } else if (blk <= padB) {
        int i = (blk - 1) * 256 + tid;
        if (i < Nc)
            posc4[i] = make_float4(posc[i * 3 + 0], posc[i * 3 + 1], posc[i * 3 + 2], 0.0f);
    } else {
        int idx = (blk - 1 - padB) * 256 + tid;
        if (idx < (TAB + 1) * F) {
            int t = idx >> 7;
            int j = idx & (F - 1);
            float dist = (float)t * (10.0f / (float)TAB);
            const float delta = 10.0f / 127.0f;
            const float coeff = -0.5f / (delta * delta);
            float d = dist - (float)j * delta;
            gs[idx] = expf(coeff * d * d);
        }
    }
}

// ---------------- row-broadcast GEMM: ctx_feat = attr @ lin1_w  [Nc,256]x[256,128] ----------------
// A-row elements are wave-uniform -> s_load into SGPRs; no LDS, VALU ~= pure FMA.
__global__ __launch_bounds__(128) void feat_kernel(const float* __restrict__ attr,
                                                   const float* __restrict__ lin1_w,
                                                   float* __restrict__ ctx_feat, int Nc) {
    int r0 = blockIdx.x * FR;
    int f = threadIdx.x;
    float acc[FR];
#pragma unroll
    for (int r = 0; r < FR; ++r) acc[r] = 0.0f;
    if (r0 + FR <= Nc) {
        for (int h = 0; h < H; h += 4) {
            float w0 = lin1_w[(h + 0) * F + f];
            float w1 = lin1_w[(h + 1) * F + f];
            float w2 = lin1_w[(h + 2) * F + f];
            float w3 = lin1_w[(h + 3) * F + f];
#pragma unroll
            for (int r = 0; r < FR; ++r) {
                const float* ap = attr + (size_t)(r0 + r) * H + h;   // wave-uniform -> s_load
                acc[r] = fmaf(ap[0], w0, acc[r]);
                acc[r] = fmaf(ap[1], w1, acc[r]);
                acc[r] = fmaf(ap[2], w2, acc[r]);
                acc[r] = fmaf(ap[3], w3, acc[r]);
            }
        }
#pragma unroll
        for (int r = 0; r < FR; ++r) ctx_feat[(size_t)(r0 + r) * F + f] = acc[r];
    } else {
        for (int r = 0; r < FR; ++r) {
            int row = r0 + r;
            if (row >= Nc) break;
            float a = 0.0f;
            for (int h = 0; h < H; ++h) a = fmaf(attr[(size_t)row * H + h], lin1_w[h * F + f], a);
            ctx_feat[(size_t)row * F + f] = a;
        }
    }
}

// ---------------- t1 = ssp(GS @ nn1 + b1)  [4097,128]x[128,128] ----------------
__global__ __launch_bounds__(128) void mlp1_kernel(const float* __restrict__ gs,
                                                   const float* __restrict__ nn1_w,
                                                   const float* __restrict__ nn1_b,
                                                   float* __restrict__ t1) {
    int r0 = blockIdx.x * FR;
    int f = threadIdx.x;
    float acc[FR];
#pragma unroll
    for (int r = 0; r < FR; ++r) acc[r] = 0.0f;
    int rmax = min(FR, (TAB + 1) - r0);
    if (rmax == FR) {
        for (int j = 0; j < F; j += 4) {
            float w0 = nn1_w[(j + 0) * F + f];
            float w1 = nn1_w[(j + 1) * F + f];
            float w2 = nn1_w[(j + 2) * F + f];
            float w3 = nn1_w[(j + 3) * F + f];
#pragma unroll
            for (int r = 0; r < FR; ++r) {
                const float* ap = gs + (size_t)(r0 + r) * F + j;
                acc[r] = fmaf(ap[0], w0, acc[r]);
                acc[r] = fmaf(ap[1], w1, acc[r]);
                acc[r] = fmaf(ap[2], w2, acc[r]);
                acc[r] = fmaf(ap[3], w3, acc[r]);
            }
        }
        float b = nn1_b[f];
#pragma unroll
        for (int r = 0; r < FR; ++r) t1[(size_t)(r0 + r) * F + f] = ssp(acc[r] + b);
    } else {
        float b = nn1_b[f];
        for (int r = 0; r < rmax; ++r) {
            float a = 0.0f;
            for (int j = 0; j < F; ++j) a = fmaf(gs[(size_t)(r0 + r) * F + j], nn1_w[j * F + f], a);
            t1[(size_t)(r0 + r) * F + f] = ssp(a + b);
        }
    }
}

// ---------------- wtab = t1 @ nn2 + b2 ----------------
__global__ __launch_bounds__(128) void mlp2_kernel(const float* __restrict__ t1,
                                                   const float* __restrict__ nn2_w,
                                                   const float* __restrict__ nn2_b,
                                                   float* __restrict__ wtab) {
    int r0 = blockIdx.x * FR;
    int f = threadIdx.x;
    float acc[FR];
#pragma unroll
    for (int r = 0; r < FR; ++r) acc[r] = 0.0f;
    int rmax = min(FR, (TAB + 1) - r0);
    if (rmax == FR) {
        for (int j = 0; j < F; j += 4) {
            float w0 = nn2_w[(j + 0) * F + f];
            float w1 = nn2_w[(j + 1) * F + f];
            float w2 = nn2_w[(j + 2) * F + f];
            float w3 = nn2_w[(j + 3) * F + f];
#pragma unroll
            for (int r = 0; r < FR; ++r) {
                const float* ap = t1 + (size_t)(r0 + r) * F + j;
                acc[r] = fmaf(ap[0], w0, acc[r]);
                acc[r] = fmaf(ap[1], w1, acc[r]);
                acc[r] = fmaf(ap[2], w2, acc[r]);
                acc[r] = fmaf(ap[3], w3, acc[r]);
            }
        }
        float b = nn2_b[f];
#pragma unroll
        for (int r = 0; r < FR; ++r) wtab[(size_t)(r0 + r) * F + f] = acc[r] + b;
    } else {
        float b = nn2_b[f];
        for (int r = 0; r < rmax; ++r) {
            float a = 0.0f;
            for (int j = 0; j < F; ++j) a = fmaf(t1[(size_t)(r0 + r) * F + j], nn2_w[j * F + f], a);
            wtab[(size_t)(r0 + r) * F + f] = a + b;
        }
    }
}

// ---------------- batch-aware kNN: wave per query, 64-bin d2 select ----------------
__global__ __launch_bounds__(256) void knn_kernel(const float* __restrict__ posq,
                                                  const float4* __restrict__ posc4,
                                                  const int* __restrict__ bq,
                                                  const int* __restrict__ ctx_start,
                                                  int* __restrict__ nbr, int Nq) {
    __shared__ unsigned char sbin[4][BINCAP];
    __shared__ int hist[4][KBINS];
    __shared__ unsigned bkey[4][BCAP];
    __shared__ int bidx[4][BCAP];
    __shared__ int s_nwin[4], s_nbnd[4];

    int tid = threadIdx.x;
    int lane = tid & 63;
    int w = tid >> 6;
    int q = blockIdx.x * 4 + w;
    bool active = q < Nq;
    int qc = active ? q : 0;

    hist[w][lane] = 0;
    if (lane == 0) { s_nwin[w] = 0; s_nbnd[w] = 0; }

    float qx = posq[qc * 3 + 0];
    float qy = posq[qc * 3 + 1];
    float qz = posq[qc * 3 + 2];
    int b = bq[qc];
    int c0 = ctx_start[b];
    int c1 = ctx_start[b + 1];
    int seg = active ? (c1 - c0) : 0;
    __syncthreads();

    const float SCALE = (float)KBINS / RCUT2;
    int farc = -1;

    // Pass A: bin every candidate; cache bin byte; histogram in-cutoff bins
    for (int i = lane; i < seg; i += 64) {
        float d2 = d2f4(posc4[c0 + i], qx, qy, qz);
        int bin = 255;
        if (d2 < RCUT2) {
            bin = (int)(d2 * SCALE);
            atomicAdd(&hist[w][bin], 1);
        }
        if (i < BINCAP) sbin[w][i] = (unsigned char)bin;
    }
    __syncthreads();

    // wave scan of own 64-bin histogram
    int h = hist[w][lane];
    int inc = h;
#pragma unroll
    for (int off = 1; off < 64; off <<= 1) {
        int v = __shfl_up(inc, off);
        if (lane >= off) inc += v;
    }
    unsigned long long bal = __ballot(inc >= K);
    int T, below;
    if (bal) {
        T = __ffsll(bal) - 1;
        below = __shfl(inc, T) - __shfl(h, T);
    } else {
        T = KBINS;           // fewer than K in cutoff: all in-cutoff bins win
        below = __shfl(inc, 63);
    }

    // Pass B: emit winners, collect boundary bin, remember one far point
    for (int i = lane; i < seg; i += 64) {
        int c = c0 + i;
        int bin;
        if (i < BINCAP) bin = sbin[w][i];
        else {
            float d2 = d2f4(posc4[c], qx, qy, qz);
            bin = (d2 < RCUT2) ? (int)(d2 * SCALE) : 255;
        }
        if (bin < T) {
            int p = atomicAdd(&s_nwin[w], 1);
            nbr[(size_t)q * K + p] = c;
        } else if (bin == T) {
            int p = atomicAdd(&s_nbnd[w], 1);
            if (p < BCAP) {
                float d2 = d2f4(posc4[c], qx, qy, qz);
                bkey[w][p] = __float_as_uint(d2);
                bidx[w][p] = c;
            }
        } else if (bin == 255) {
            farc = c;
        }
    }
#pragma unroll
    for (int off = 1; off < 64; off <<= 1) farc = max(farc, __shfl_xor(farc, off));
    if (farc < 0) farc = c0;
    __syncthreads();

    if (!active) return;
    int nb = min(s_nbnd[w], BCAP);
    int m = K - s_nwin[w];
    // wave-serial: pick m smallest from boundary list (expected ~4-8)
    for (int it = 0; it < m; ++it) {
        unsigned bestk = 0xFFFFFFFFu;
        int bestp = -1;
        for (int p = lane; p < nb; p += 64) {
            unsigned kk = bkey[w][p];
            if (kk < bestk) { bestk = kk; bestp = p; }
        }
#pragma unroll
        for (int off = 1; off < 64; off <<= 1) {
            unsigned ok = __shfl_xor(bestk, off);
            int op = __shfl_xor(bestp, off);
            if (ok < bestk) { bestk = ok; bestp = op; }
        }
        if (lane == 0) {
            if (bestk != 0xFFFFFFFFu && bestp >= 0) {
                nbr[(size_t)q * K + below + it] = bidx[w][bestp];
                bkey[w][bestp] = 0xFFFFFFFFu;
            } else {
                nbr[(size_t)q * K + below + it] = farc;   // pad: contributes 0
            }
        }
        __asm__ volatile("" ::: "memory");
    }
}

// ---------------- per-query edge aggregation: acc_f = sum_k C_k * W_k[f] * a_k[f] ----------------
__global__ __launch_bounds__(128) void agg_kernel(const float* __restrict__ posq,
                                                  const float4* __restrict__ posc4,
                                                  const int* __restrict__ nbr,
                                                  const float* __restrict__ ctx_feat,
                                                  const float* __restrict__ wtab,
                                                  float* __restrict__ yacc,
                                                  float* __restrict__ ysc, int Nq) {
    int q = blockIdx.x;
    int f = threadIdx.x;
    __shared__ int sj[K];
    __shared__ int si0[K];
    __shared__ float sC[K];
    __shared__ float sfr[K];

    if (f < K) {
        int j = nbr[(size_t)q * K + f];
        sj[f] = j;
        float4 p = posc4[j];
        float dx = posq[q * 3 + 0] - p.x;
        float dy = posq[q * 3 + 1] - p.y;
        float dz = posq[q * 3 + 2] - p.z;
        float dist = sqrtf(dx * dx + dy * dy + dz * dz);
        float C = 0.0f, fr = 0.0f;
        int i0 = 0;
        if (dist <= 10.0f) {
            C = 0.5f * (cosf(dist * 0.31415926535897931f) + 1.0f);
            float u = dist * ((float)TAB / 10.0f);
            i0 = (int)u;
            if (i0 > TAB - 1) i0 = TAB - 1;
            fr = u - (float)i0;
        }
        sC[f] = C; si0[f] = i0; sfr[f] = fr;
    }
    __syncthreads();

    float acc = 0.0f;
    float csum = 0.0f;
    for (int k = 0; k < K; ++k) {
        float C = sC[k];
        csum += C;
        if (C == 0.0f) continue;
        int i0 = si0[k];
        float fr = sfr[k];
        int j = sj[k];
        float w0 = wtab[(size_t)i0 * F + f];
        float w1 = wtab[(size_t)(i0 + 1) * F + f];
        float W = w0 + fr * (w1 - w0);
        float a = ctx_feat[(size_t)j * F + f];
        acc += C * (W * a);
    }
    yacc[(size_t)q * F + f] = acc;
    if (f == 0) ysc[q] = csum;
}

// ---------------- heads: y = acc@lin2 + sC*lin2_b; cls/prop MLPs ----------------
// 256 threads: f = tid&127 (output feature), g = tid>>7 (query half, 4 queries each)
__global__ __launch_bounds__(256) void head_kernel(const float* __restrict__ yacc,
                                                   const float* __restrict__ ysc,
                                                   const float* __restrict__ lin2_w,
                                                   const float* __restrict__ lin2_b,
                                                   const float* __restrict__ cls1_w,
                                                   const float* __restrict__ cls1_b,
                                                   const float* __restrict__ cls2_w,
                                                   const float* __restrict__ cls2_b,
                                                   const float* __restrict__ prop1_w,
                                                   const float* __restrict__ prop1_b,
                                                   const float* __restrict__ prop2_w,
                                                   const float* __restrict__ prop2_b,
                                                   float* __restrict__ out_cls,
                                                   float* __restrict__ out_ind, int Nq) {
    const int QH = QB / 2;   // 4 queries per thread-group
    int q0 = blockIdx.x * QB;
    int tid = threadIdx.x;
    int f = tid & (F - 1);
    int g = tid >> 7;

    __shared__ float sa[QB][F];       // yacc rows (broadcast-read only)
    __shared__ float ssc[QB];
    __shared__ float sy[QB][FP];      // padded: 16B-aligned rows, bank-skewed
    __shared__ float sc1[QB][FP];
    __shared__ float sp1[QB][FP];

    // stage yacc rows: one coalesced float4 load (QB*F/4 == 256)
    if (q0 + QB <= Nq) {
        ((float4*)sa)[tid] = ((const float4*)(yacc + (size_t)q0 * F))[tid];
    } else {
        for (int i = tid; i < QB * F; i += 256) {
            int qq = i >> 7;
            sa[qq][i & (F - 1)] = (q0 + qq < Nq) ? yacc[(size_t)(q0 + qq) * F + (i & (F - 1))] : 0.0f;
        }
    }
    if (tid < QB) ssc[tid] = (q0 + tid < Nq) ? ysc[q0 + tid] : 0.0f;
    __syncthreads();

    // ---- stage A: y = sa @ lin2_w + ssc*lin2_b (each thread: 4 queries) ----
    {
        float y[QH];
        float lb = lin2_b[f];
#pragma unroll
        for (int i = 0; i < QH; ++i) y[i] = ssc[g * QH + i] * lb;
        for (int j = 0; j < F; j += 4) {
            float w0 = lin2_w[(j + 0) * F + f];
            float w1 = lin2_w[(j + 1) * F + f];
            float w2 = lin2_w[(j + 2) * F + f];
            float w3 = lin2_w[(j + 3) * F + f];
#pragma unroll
            for (int i = 0; i < QH; ++i) {
                float4 a4 = *(const float4*)&sa[g * QH + i][j];
                y[i] = fmaf(a4.x, w0, y[i]);
                y[i] = fmaf(a4.y, w1, y[i]);
                y[i] = fmaf(a4.z, w2, y[i]);
                y[i] = fmaf(a4.w, w3, y[i]);
            }
        }
#pragma unroll
        for (int i = 0; i < QH; ++i) sy[g * QH + i][f] = y[i];
    }
    __syncthreads();

    // ---- stage B: c1 = ssp(y@cls1+b), p1 = ssp(y@prop1+b) ----
    {
        float c1[QH], p1[QH];
        float cb = cls1_b[f], pb = prop1_b[f];
#pragma unroll
        for (int i = 0; i < QH; ++i) { c1[i] = cb; p1[i] = pb; }
        for (int j = 0; j < F; j += 4) {
            float wc0 = cls1_w[(j + 0) * F + f];
            float wc1 = cls1_w[(j + 1) * F + f];
            float wc2 = cls1_w[(j + 2) * F + f];
            float wc3 = cls1_w[(j + 3) * F + f];
            float wp0 = prop1_w[(j + 0) * F + f];
            float wp1 = prop1_w[(j + 1) * F + f];
            float wp2 = prop1_w[(j + 2) * F + f];
            float wp3 = prop1_w[(j + 3) * F + f];
#pragma unroll
            for (int i = 0; i < QH; ++i) {
                float4 y4 = *(const float4*)&sy[g * QH + i][j];
                c1[i] = fmaf(y4.x, wc0, c1[i]);
                c1[i] = fmaf(y4.y, wc1, c1[i]);
                c1[i] = fmaf(y4.z, wc2, c1[i]);
                c1[i] = fmaf(y4.w, wc3, c1[i]);
                p1[i] = fmaf(y4.x, wp0, p1[i]);
                p1[i] = fmaf(y4.y, wp1, p1[i]);
                p1[i] = fmaf(y4.z, wp2, p1[i]);
                p1[i] = fmaf(y4.w, wp3, p1[i]);
            }
        }
#pragma unroll
        for (int i = 0; i < QH; ++i) {
            sc1[g * QH + i][f] = ssp(c1[i]);
            sp1[g * QH + i][f] = ssp(p1[i]);
        }
    }
    __syncthreads();

    // ---- tails: 8 queries x 15 outputs; 32 threads per query, c<15 active ----
    {
        int qq = tid >> 5;            // 0..7
        int c = tid & 31;             // 0..31
        int q = q0 + qq;
        if (q < Nq && c < 15) {
            if (c < 7) {
                float acc = cls2_b[c];
                for (int j = 0; j < F; ++j) acc = fmaf(sc1[qq][j], cls2_w[j * 7 + c], acc);
                out_cls[(size_t)q * 7 + c] = acc;
            } else {
                int cc = c - 7;
                float acc = prop2_b[cc];
                for (int j = 0; j < F; ++j) acc = fmaf(sp1[qq][j], prop2_w[j * 8 + cc], acc);
                out_ind[(size_t)q * 8 + cc] = acc;
            }
        }
    }
}

extern "C" void kernel_launch(void* const* d_in, const int* in_sizes, int n_in,
                              void* d_out, int out_size, void* d_ws, size_t ws_size,
                              hipStream_t stream) {
    const float* posq   = (const float*)d_in[0];
    const float* posc   = (const float*)d_in[1];
    const float* attr   = (const float*)d_in[2];
    const int*   bq     = (const int*)d_in[3];
    const int*   bc     = (const int*)d_in[4];
    const float* lin1_w = (const float*)d_in[5];
    const float* lin2_w = (const float*)d_in[6];
    const float* lin2_b = (const float*)d_in[7];
    const float* nn1_w  = (const float*)d_in[8];
    const float* nn1_b  = (const float*)d_in[9];
    const float* nn2_w  = (const float*)d_in[10];
    const float* nn2_b  = (const float*)d_in[11];
    const float* cls1_w = (const float*)d_in[12];
    const float* cls1_b = (const float*)d_in[13];
    const float* cls2_w = (const float*)d_in[14];
    const float* cls2_b = (const float*)d_in[15];
    const float* prop1_w = (const float*)d_in[16];
    const float* prop1_b = (const float*)d_in[17];
    const float* prop2_w = (const float*)d_in[18];
    const float* prop2_b = (const float*)d_in[19];

    int Nq = in_sizes[0] / 3;
    int Nc = in_sizes[1] / 3;

    char* ws = (char*)d_ws;
    size_t off = 0;
    auto alloc = [&](size_t bytes) {
        off = (off + 255) & ~(size_t)255;
        void* p = ws + off;
        off += bytes;
        return p;
    };
    int*    ctx_start = (int*)alloc((BMAX + 1) * sizeof(int));
    int*    nbr       = (int*)alloc((size_t)Nq * K * sizeof(int));
    float*  ctx_feat  = (float*)alloc((size_t)Nc * F * sizeof(float));
    float*  wtab      = (float*)alloc((size_t)(TAB + 1) * F * sizeof(float));
    float*  yacc      = (float*)alloc((size_t)Nq * F * sizeof(float));
    float*  ysc       = (float*)alloc((size_t)Nq * sizeof(float));
    float4* posc4     = (float4*)alloc((size_t)Nc * sizeof(float4));
    float*  gsbuf     = (float*)alloc((size_t)(TAB + 1) * F * sizeof(float));
    float*  t1buf     = (float*)alloc((size_t)(TAB + 1) * F * sizeof(float));
    (void)ws_size;

    float* out_cls = (float*)d_out;
    float* out_ind = out_cls + (size_t)Nq * 7;

    int padB = (Nc + 255) / 256;
    int gsB = ((TAB + 1) * F + 255) / 256;
    int mlpB = ((TAB + 1) + FR - 1) / FR;

    prep_kernel<<<dim3(1 + padB + gsB), dim3(256), 0, stream>>>(bc, Nc, ctx_start, posc, posc4, gsbuf, padB);
    knn_kernel<<<dim3((Nq + 3) / 4), dim3(256), 0, stream>>>(posq, posc4, bq, ctx_start, nbr, Nq);
    feat_kernel<<<dim3((Nc + FR - 1) / FR), dim3(128), 0, stream>>>(attr, lin1_w, ctx_feat, Nc);
    mlp1_kernel<<<dim3(mlpB), dim3(128), 0, stream>>>(gsbuf, nn1_w, nn1_b, t1buf);
    mlp2_kernel<<<dim3(mlpB), dim3(128), 0, stream>>>(t1buf, nn2_w, nn2_b, wtab);
    agg_kernel<<<dim3(Nq), dim3(128), 0, stream>>>(posq, posc4, nbr, ctx_feat, wtab, yacc, ysc, Nq);
    head_kernel<<<dim3((Nq + QB - 1) / QB), dim3(256), 0, stream>>>(
        yacc, ysc, lin2_w, lin2_b, cls1_w, cls1_b, cls2_w, cls2_b,
        prop1_w, prop1_b, prop2_w, prop2_b, out_cls, out_ind, Nq);
}

// Round 6
// 163.964 us; speedup vs baseline: 1.4623x; 1.4623x over previous
//
#include <hip/hip_runtime.h>
#include <math.h>

#define K 32
#define F 128
#define H 256
#define TAB 4096
#define QB 8
#define BMAX 16
#define RCUT2 100.0f
#define KBINS 64
#define BINCAP 2560
#define BCAP 128
#define FP 132   // padded LDS row stride (16B-aligned, bank-skewed)
#define FRR 16   // rows per block in feat/wtab GEMMs

__device__ __forceinline__ float ssp(float x) {
    // jax.nn.softplus(x) - log(2)
    return fmaxf(x, 0.0f) + log1pf(expf(-fabsf(x))) - 0.69314718055994531f;
}

// d2 with pinned fma contraction so pass A and pass B agree bit-exactly
__device__ __forceinline__ float d2f4(float4 p, float qx, float qy, float qz) {
    float dx = qx - p.x;
    float dy = qy - p.y;
    float dz = qz - p.z;
    return fmaf(dz, dz, fmaf(dy, dy, dx * dx));
}

// ---------------- prep: seg boundaries + pos padding ----------------
__global__ __launch_bounds__(256) void prep_kernel(const int* __restrict__ bc, int Nc,
                                                   int* __restrict__ ctx_start,
                                                   const float* __restrict__ posc,
                                                   float4* __restrict__ posc4) {
    int blk = blockIdx.x;
    int tid = threadIdx.x;
    if (blk == 0) {
        if (tid <= BMAX) {
            int b = tid;
            int lo = 0, hi = Nc;
            while (lo < hi) {
                int mid = (lo + hi) >> 1;
                if (bc[mid] < b) lo = mid + 1; else hi = mid;
            }
            ctx_start[b] = lo;
        }
    } else {
        int i = (blk - 1) * 256 + tid;
        if (i < Nc)
            posc4[i] = make_float4(posc[i * 3 + 0], posc[i * 3 + 1], posc[i * 3 + 2], 0.0f);
    }
}

// ---------------- ctx_feat = attr @ lin1_w : LDS-staged A, b128 broadcast reads ----------------
// 256 threads: f = tid&127 (out col), g = tid>>7 (row half: 8 rows each). DS:FMA = 1:4.
__global__ __launch_bounds__(256) void feat_kernel(const float* __restrict__ attr,
                                                   const float* __restrict__ lin1_w,
                                                   float* __restrict__ ctx_feat, int Nc) {
    __shared__ float sa[FRR][H];   // 16 KB
    int r0 = blockIdx.x * FRR;
    int tid = threadIdx.x;
    int f = tid & (F - 1);
    int g = tid >> 7;

    // stage 16 rows, coalesced float4
    {
        float4* dst = (float4*)sa;
        const int total = FRR * H / 4;   // 1024
        if (r0 + FRR <= Nc) {
            const float4* src = (const float4*)(attr + (size_t)r0 * H);
            for (int i = tid; i < total; i += 256) dst[i] = src[i];
        } else {
            for (int i = tid; i < total; i += 256) {
                int r = i / (H / 4);
                if (r0 + r < Nc) dst[i] = ((const float4*)(attr + (size_t)r0 * H))[i];
                else dst[i] = make_float4(0.0f, 0.0f, 0.0f, 0.0f);
            }
        }
    }
    __syncthreads();

    float acc[8];
#pragma unroll
    for (int r = 0; r < 8; ++r) acc[r] = 0.0f;
    for (int k = 0; k < H; k += 4) {
        float w0 = lin1_w[(k + 0) * F + f];
        float w1 = lin1_w[(k + 1) * F + f];
        float w2 = lin1_w[(k + 2) * F + f];
        float w3 = lin1_w[(k + 3) * F + f];
#pragma unroll
        for (int r = 0; r < 8; ++r) {
            float4 a4 = *(const float4*)&sa[g * 8 + r][k];   // uniform addr -> LDS broadcast
            acc[r] = fmaf(a4.x, w0, acc[r]);
            acc[r] = fmaf(a4.y, w1, acc[r]);
            acc[r] = fmaf(a4.z, w2, acc[r]);
            acc[r] = fmaf(a4.w, w3, acc[r]);
        }
    }
#pragma unroll
    for (int r = 0; r < 8; ++r) {
        int row = r0 + g * 8 + r;
        if (row < Nc) ctx_feat[(size_t)row * F + f] = acc[r];
    }
}

// ---------------- fused wtab: gs -> ssp(gs@nn1+b1) -> @nn2+b2, 16 t-rows/block ----------------
__global__ __launch_bounds__(128) void wtab_kernel(const float* __restrict__ nn1_w,
                                                   const float* __restrict__ nn1_b,
                                                   const float* __restrict__ nn2_w,
                                                   const float* __restrict__ nn2_b,
                                                   float* __restrict__ wtab) {
    __shared__ float sg[FRR][F];   // 8 KB
    __shared__ float st[FRR][F];   // 8 KB
    int r0 = blockIdx.x * FRR;
    int f = threadIdx.x;
    int rmax = min(FRR, (TAB + 1) - r0);

    const float delta = 10.0f / 127.0f;
    const float coeff = -0.5f / (delta * delta);
    float off = (float)f * delta;
#pragma unroll
    for (int r = 0; r < FRR; ++r) {
        float dist = (float)(r0 + r) * (10.0f / (float)TAB);
        float d = dist - off;
        sg[r][f] = expf(coeff * d * d);
    }
    __syncthreads();

    float acc[FRR];
#pragma unroll
    for (int r = 0; r < FRR; ++r) acc[r] = 0.0f;
    for (int j = 0; j < F; j += 4) {
        float w0 = nn1_w[(j + 0) * F + f];
        float w1 = nn1_w[(j + 1) * F + f];
        float w2 = nn1_w[(j + 2) * F + f];
        float w3 = nn1_w[(j + 3) * F + f];
#pragma unroll
        for (int r = 0; r < FRR; ++r) {
            float4 a4 = *(const float4*)&sg[r][j];
            acc[r] = fmaf(a4.x, w0, acc[r]);
            acc[r] = fmaf(a4.y, w1, acc[r]);
            acc[r] = fmaf(a4.z, w2, acc[r]);
            acc[r] = fmaf(a4.w, w3, acc[r]);
        }
    }
    float b1 = nn1_b[f];
#pragma unroll
    for (int r = 0; r < FRR; ++r) st[r][f] = ssp(acc[r] + b1);
    __syncthreads();

#pragma unroll
    for (int r = 0; r < FRR; ++r) acc[r] = 0.0f;
    for (int j = 0; j < F; j += 4) {
        float w0 = nn2_w[(j + 0) * F + f];
        float w1 = nn2_w[(j + 1) * F + f];
        float w2 = nn2_w[(j + 2) * F + f];
        float w3 = nn2_w[(j + 3) * F + f];
#pragma unroll
        for (int r = 0; r < FRR; ++r) {
            float4 a4 = *(const float4*)&st[r][j];
            acc[r] = fmaf(a4.x, w0, acc[r]);
            acc[r] = fmaf(a4.y, w1, acc[r]);
            acc[r] = fmaf(a4.z, w2, acc[r]);
            acc[r] = fmaf(a4.w, w3, acc[r]);
        }
    }
    float b2 = nn2_b[f];
    for (int r = 0; r < rmax; ++r) wtab[(size_t)(r0 + r) * F + f] = acc[r] + b2;
}

// ---------------- batch-aware kNN: wave per query, 64-bin d2 select ----------------
__global__ __launch_bounds__(256) void knn_kernel(const float* __restrict__ posq,
                                                  const float4* __restrict__ posc4,
                                                  const int* __restrict__ bq,
                                                  const int* __restrict__ ctx_start,
                                                  int* __restrict__ nbr, int Nq) {
    __shared__ unsigned char sbin[4][BINCAP];
    __shared__ int hist[4][KBINS];
    __shared__ unsigned bkey[4][BCAP];
    __shared__ int bidx[4][BCAP];
    __shared__ int s_nwin[4], s_nbnd[4];

    int tid = threadIdx.x;
    int lane = tid & 63;
    int w = tid >> 6;
    int q = blockIdx.x * 4 + w;
    bool active = q < Nq;
    int qc = active ? q : 0;

    hist[w][lane] = 0;
    if (lane == 0) { s_nwin[w] = 0; s_nbnd[w] = 0; }

    float qx = posq[qc * 3 + 0];
    float qy = posq[qc * 3 + 1];
    float qz = posq[qc * 3 + 2];
    int b = bq[qc];
    int c0 = ctx_start[b];
    int c1 = ctx_start[b + 1];
    int seg = active ? (c1 - c0) : 0;
    __syncthreads();

    const float SCALE = (float)KBINS / RCUT2;
    int farc = -1;

    // Pass A: bin every candidate; cache bin byte; histogram in-cutoff bins
    for (int i = lane; i < seg; i += 64) {
        float d2 = d2f4(posc4[c0 + i], qx, qy, qz);
        int bin = 255;
        if (d2 < RCUT2) {
            bin = (int)(d2 * SCALE);
            atomicAdd(&hist[w][bin], 1);
        }
        if (i < BINCAP) sbin[w][i] = (unsigned char)bin;
    }
    __syncthreads();

    // wave scan of own 64-bin histogram
    int h = hist[w][lane];
    int inc = h;
#pragma unroll
    for (int off = 1; off < 64; off <<= 1) {
        int v = __shfl_up(inc, off);
        if (lane >= off) inc += v;
    }
    unsigned long long bal = __ballot(inc >= K);
    int T, below;
    if (bal) {
        T = __ffsll(bal) - 1;
        below = __shfl(inc, T) - __shfl(h, T);
    } else {
        T = KBINS;           // fewer than K in cutoff: all in-cutoff bins win
        below = __shfl(inc, 63);
    }

    // Pass B: emit winners, collect boundary bin, remember one far point
    for (int i = lane; i < seg; i += 64) {
        int c = c0 + i;
        int bin;
        if (i < BINCAP) bin = sbin[w][i];
        else {
            float d2 = d2f4(posc4[c], qx, qy, qz);
            bin = (d2 < RCUT2) ? (int)(d2 * SCALE) : 255;
        }
        if (bin < T) {
            int p = atomicAdd(&s_nwin[w], 1);
            nbr[(size_t)q * K + p] = c;
        } else if (bin == T) {
            int p = atomicAdd(&s_nbnd[w], 1);
            if (p < BCAP) {
                float d2 = d2f4(posc4[c], qx, qy, qz);
                bkey[w][p] = __float_as_uint(d2);
                bidx[w][p] = c;
            }
        } else if (bin == 255) {
            farc = c;
        }
    }
#pragma unroll
    for (int off = 1; off < 64; off <<= 1) farc = max(farc, __shfl_xor(farc, off));
    if (farc < 0) farc = c0;
    __syncthreads();

    if (!active) return;
    int nb = min(s_nbnd[w], BCAP);
    int m = K - s_nwin[w];
    // wave-serial: pick m smallest from boundary list (expected ~4-8)
    for (int it = 0; it < m; ++it) {
        unsigned bestk = 0xFFFFFFFFu;
        int bestp = -1;
        for (int p = lane; p < nb; p += 64) {
            unsigned kk = bkey[w][p];
            if (kk < bestk) { bestk = kk; bestp = p; }
        }
#pragma unroll
        for (int off = 1; off < 64; off <<= 1) {
            unsigned ok = __shfl_xor(bestk, off);
            int op = __shfl_xor(bestp, off);
            if (ok < bestk) { bestk = ok; bestp = op; }
        }
        if (lane == 0) {
            if (bestk != 0xFFFFFFFFu && bestp >= 0) {
                nbr[(size_t)q * K + below + it] = bidx[w][bestp];
                bkey[w][bestp] = 0xFFFFFFFFu;
            } else {
                nbr[(size_t)q * K + below + it] = farc;   // pad: contributes 0
            }
        }
        __asm__ volatile("" ::: "memory");
    }
}

// ---------------- per-query edge aggregation: acc_f = sum_k C_k * W_k[f] * a_k[f] ----------------
__global__ __launch_bounds__(128) void agg_kernel(const float* __restrict__ posq,
                                                  const float4* __restrict__ posc4,
                                                  const int* __restrict__ nbr,
                                                  const float* __restrict__ ctx_feat,
                                                  const float* __restrict__ wtab,
                                                  float* __restrict__ yacc,
                                                  float* __restrict__ ysc, int Nq) {
    int q = blockIdx.x;
    int f = threadIdx.x;
    __shared__ int sj[K];
    __shared__ int si0[K];
    __shared__ float sC[K];
    __shared__ float sfr[K];

    if (f < K) {
        int j = nbr[(size_t)q * K + f];
        sj[f] = j;
        float4 p = posc4[j];
        float dx = posq[q * 3 + 0] - p.x;
        float dy = posq[q * 3 + 1] - p.y;
        float dz = posq[q * 3 + 2] - p.z;
        float dist = sqrtf(dx * dx + dy * dy + dz * dz);
        float C = 0.0f, fr = 0.0f;
        int i0 = 0;
        if (dist <= 10.0f) {
            C = 0.5f * (cosf(dist * 0.31415926535897931f) + 1.0f);
            float u = dist * ((float)TAB / 10.0f);
            i0 = (int)u;
            if (i0 > TAB - 1) i0 = TAB - 1;
            fr = u - (float)i0;
        }
        sC[f] = C; si0[f] = i0; sfr[f] = fr;
    }
    __syncthreads();

    float acc = 0.0f;
    float csum = 0.0f;
    for (int k = 0; k < K; ++k) {
        float C = sC[k];
        csum += C;
        if (C == 0.0f) continue;
        int i0 = si0[k];
        float fr = sfr[k];
        int j = sj[k];
        float w0 = wtab[(size_t)i0 * F + f];
        float w1 = wtab[(size_t)(i0 + 1) * F + f];
        float W = w0 + fr * (w1 - w0);
        float a = ctx_feat[(size_t)j * F + f];
        acc += C * (W * a);
    }
    yacc[(size_t)q * F + f] = acc;
    if (f == 0) ysc[q] = csum;
}

// ---------------- heads: y = acc@lin2 + sC*lin2_b; cls/prop MLPs ----------------
// 256 threads: f = tid&127 (output feature), g = tid>>7 (query half, 4 queries each)
__global__ __launch_bounds__(256) void head_kernel(const float* __restrict__ yacc,
                                                   const float* __restrict__ ysc,
                                                   const float* __restrict__ lin2_w,
                                                   const float* __restrict__ lin2_b,
                                                   const float* __restrict__ cls1_w,
                                                   const float* __restrict__ cls1_b,
                                                   const float* __restrict__ cls2_w,
                                                   const float* __restrict__ cls2_b,
                                                   const float* __restrict__ prop1_w,
                                                   const float* __restrict__ prop1_b,
                                                   const float* __restrict__ prop2_w,
                                                   const float* __restrict__ prop2_b,
                                                   float* __restrict__ out_cls,
                                                   float* __restrict__ out_ind, int Nq) {
    const int QH = QB / 2;   // 4 queries per thread-group
    int q0 = blockIdx.x * QB;
    int tid = threadIdx.x;
    int f = tid & (F - 1);
    int g = tid >> 7;

    __shared__ float sa[QB][F];       // yacc rows (broadcast-read only)
    __shared__ float ssc[QB];
    __shared__ float sy[QB][FP];      // padded: 16B-aligned rows, bank-skewed
    __shared__ float sc1[QB][FP];
    __shared__ float sp1[QB][FP];

    // stage yacc rows: one coalesced float4 load (QB*F/4 == 256)
    if (q0 + QB <= Nq) {
        ((float4*)sa)[tid] = ((const float4*)(yacc + (size_t)q0 * F))[tid];
    } else {
        for (int i = tid; i < QB * F; i += 256) {
            int qq = i >> 7;
            sa[qq][i & (F - 1)] = (q0 + qq < Nq) ? yacc[(size_t)(q0 + qq) * F + (i & (F - 1))] : 0.0f;
        }
    }
    if (tid < QB) ssc[tid] = (q0 + tid < Nq) ? ysc[q0 + tid] : 0.0f;
    __syncthreads();

    // ---- stage A: y = sa @ lin2_w + ssc*lin2_b (each thread: 4 queries) ----
    {
        float y[QH];
        float lb = lin2_b[f];
#pragma unroll
        for (int i = 0; i < QH; ++i) y[i] = ssc[g * QH + i] * lb;
        for (int j = 0; j < F; j += 4) {
            float w0 = lin2_w[(j + 0) * F + f];
            float w1 = lin2_w[(j + 1) * F + f];
            float w2 = lin2_w[(j + 2) * F + f];
            float w3 = lin2_w[(j + 3) * F + f];
#pragma unroll
            for (int i = 0; i < QH; ++i) {
                float4 a4 = *(const float4*)&sa[g * QH + i][j];
                y[i] = fmaf(a4.x, w0, y[i]);
                y[i] = fmaf(a4.y, w1, y[i]);
                y[i] = fmaf(a4.z, w2, y[i]);
                y[i] = fmaf(a4.w, w3, y[i]);
            }
        }
#pragma unroll
        for (int i = 0; i < QH; ++i) sy[g * QH + i][f] = y[i];
    }
    __syncthreads();

    // ---- stage B: c1 = ssp(y@cls1+b), p1 = ssp(y@prop1+b) ----
    {
        float c1[QH], p1[QH];
        float cb = cls1_b[f], pb = prop1_b[f];
#pragma unroll
        for (int i = 0; i < QH; ++i) { c1[i] = cb; p1[i] = pb; }
        for (int j = 0; j < F; j += 4) {
            float wc0 = cls1_w[(j + 0) * F + f];
            float wc1 = cls1_w[(j + 1) * F + f];
            float wc2 = cls1_w[(j + 2) * F + f];
            float wc3 = cls1_w[(j + 3) * F + f];
            float wp0 = prop1_w[(j + 0) * F + f];
            float wp1 = prop1_w[(j + 1) * F + f];
            float wp2 = prop1_w[(j + 2) * F + f];
            float wp3 = prop1_w[(j + 3) * F + f];
#pragma unroll
            for (int i = 0; i < QH; ++i) {
                float4 y4 = *(const float4*)&sy[g * QH + i][j];
                c1[i] = fmaf(y4.x, wc0, c1[i]);
                c1[i] = fmaf(y4.y, wc1, c1[i]);
                c1[i] = fmaf(y4.z, wc2, c1[i]);
                c1[i] = fmaf(y4.w, wc3, c1[i]);
                p1[i] = fmaf(y4.x, wp0, p1[i]);
                p1[i] = fmaf(y4.y, wp1, p1[i]);
                p1[i] = fmaf(y4.z, wp2, p1[i]);
                p1[i] = fmaf(y4.w, wp3, p1[i]);
            }
        }
#pragma unroll
        for (int i = 0; i < QH; ++i) {
            sc1[g * QH + i][f] = ssp(c1[i]);
            sp1[g * QH + i][f] = ssp(p1[i]);
        }
    }
    __syncthreads();

    // ---- tails: 8 queries x 15 outputs; 32 threads per query, c<15 active ----
    {
        int qq = tid >> 5;            // 0..7
        int c = tid & 31;             // 0..31
        int q = q0 + qq;
        if (q < Nq && c < 15) {
            if (c < 7) {
                float acc = cls2_b[c];
                for (int j = 0; j < F; ++j) acc = fmaf(sc1[qq][j], cls2_w[j * 7 + c], acc);
                out_cls[(size_t)q * 7 + c] = acc;
            } else {
                int cc = c - 7;
                float acc = prop2_b[cc];
                for (int j = 0; j < F; ++j) acc = fmaf(sp1[qq][j], prop2_w[j * 8 + cc], acc);
                out_ind[(size_t)q * 8 + cc] = acc;
            }
        }
    }
}

extern "C" void kernel_launch(void* const* d_in, const int* in_sizes, int n_in,
                              void* d_out, int out_size, void* d_ws, size_t ws_size,
                              hipStream_t stream) {
    const float* posq   = (const float*)d_in[0];
    const float* posc   = (const float*)d_in[1];
    const float* attr   = (const float*)d_in[2];
    const int*   bq     = (const int*)d_in[3];
    const int*   bc     = (const int*)d_in[4];
    const float* lin1_w = (const float*)d_in[5];
    const float* lin2_w = (const float*)d_in[6];
    const float* lin2_b = (const float*)d_in[7];
    const float* nn1_w  = (const float*)d_in[8];
    const float* nn1_b  = (const float*)d_in[9];
    const float* nn2_w  = (const float*)d_in[10];
    const float* nn2_b  = (const float*)d_in[11];
    const float* cls1_w = (const float*)d_in[12];
    const float* cls1_b = (const float*)d_in[13];
    const float* cls2_w = (const float*)d_in[14];
    const float* cls2_b = (const float*)d_in[15];
    const float* prop1_w = (const float*)d_in[16];
    const float* prop1_b = (const float*)d_in[17];
    const float* prop2_w = (const float*)d_in[18];
    const float* prop2_b = (const float*)d_in[19];

    int Nq = in_sizes[0] / 3;
    int Nc = in_sizes[1] / 3;

    char* ws = (char*)d_ws;
    size_t off = 0;
    auto alloc = [&](size_t bytes) {
        off = (off + 255) & ~(size_t)255;
        void* p = ws + off;
        off += bytes;
        return p;
    };
    int*    ctx_start = (int*)alloc((BMAX + 1) * sizeof(int));
    int*    nbr       = (int*)alloc((size_t)Nq * K * sizeof(int));
    float*  ctx_feat  = (float*)alloc((size_t)Nc * F * sizeof(float));
    float*  wtab      = (float*)alloc((size_t)(TAB + 1) * F * sizeof(float));
    float*  yacc      = (float*)alloc((size_t)Nq * F * sizeof(float));
    float*  ysc       = (float*)alloc((size_t)Nq * sizeof(float));
    float4* posc4     = (float4*)alloc((size_t)Nc * sizeof(float4));
    (void)ws_size;

    float* out_cls = (float*)d_out;
    float* out_ind = out_cls + (size_t)Nq * 7;

    int padB = (Nc + 255) / 256;

    prep_kernel<<<dim3(1 + padB), dim3(256), 0, stream>>>(bc, Nc, ctx_start, posc, posc4);
    knn_kernel<<<dim3((Nq + 3) / 4), dim3(256), 0, stream>>>(posq, posc4, bq, ctx_start, nbr, Nq);
    feat_kernel<<<dim3((Nc + FRR - 1) / FRR), dim3(256), 0, stream>>>(attr, lin1_w, ctx_feat, Nc);
    wtab_kernel<<<dim3((TAB + 1 + FRR - 1) / FRR), dim3(128), 0, stream>>>(nn1_w, nn1_b, nn2_w, nn2_b, wtab);
    agg_kernel<<<dim3(Nq), dim3(128), 0, stream>>>(posq, posc4, nbr, ctx_feat, wtab, yacc, ysc, Nq);
    head_kernel<<<dim3((Nq + QB - 1) / QB), dim3(256), 0, stream>>>(
        yacc, ysc, lin2_w, lin2_b, cls1_w, cls1_b, cls2_w, cls2_b,
        prop1_w, prop1_b, prop2_w, prop2_b, out_cls, out_ind, Nq);
}

// Round 7
// 143.913 us; speedup vs baseline: 1.6660x; 1.1393x over previous
//
#include <hip/hip_runtime.h>
#include <math.h>

#define K 32
#define F 128
#define H 256
#define TAB 4096
#define QB 8
#define BMAX 16
#define RCUT2 100.0f
#define KBINS 64
#define BINCAP 2560
#define BCAP 128
#define FP 132   // padded LDS row stride
#define FRR 16   // rows per block in feat/wtab GEMMs

__device__ __forceinline__ float ssp(float x) {
    return fmaxf(x, 0.0f) + log1pf(expf(-fabsf(x))) - 0.69314718055994531f;
}

__device__ __forceinline__ float d2f4(float4 p, float qx, float qy, float qz) {
    float dx = qx - p.x;
    float dy = qy - p.y;
    float dz = qz - p.z;
    return fmaf(dz, dz, fmaf(dy, dy, dx * dx));
}

// ---------------- prep: seg boundaries + pos padding ----------------
__global__ __launch_bounds__(256) void prep_kernel(const int* __restrict__ bc, int Nc,
                                                   int* __restrict__ ctx_start,
                                                   const float* __restrict__ posc,
                                                   float4* __restrict__ posc4) {
    int blk = blockIdx.x;
    int tid = threadIdx.x;
    if (blk == 0) {
        if (tid <= BMAX) {
            int b = tid;
            int lo = 0, hi = Nc;
            while (lo < hi) {
                int mid = (lo + hi) >> 1;
                if (bc[mid] < b) lo = mid + 1; else hi = mid;
            }
            ctx_start[b] = lo;
        }
    } else {
        int i = (blk - 1) * 256 + tid;
        if (i < Nc)
            posc4[i] = make_float4(posc[i * 3 + 0], posc[i * 3 + 1], posc[i * 3 + 2], 0.0f);
    }
}

// ================= phase2 bodies (share one LDS union) =================

__device__ __forceinline__ void feat_body(char* smem, const float* __restrict__ attr,
                                          const float* __restrict__ lin1_w,
                                          float* __restrict__ ctx_feat, int Nc,
                                          int blk, int tid) {
    float (*sa)[H] = (float (*)[H])smem;   // 16 KB
    int r0 = blk * FRR;
    int f = tid & (F - 1);
    int g = tid >> 7;

    {
        float4* dst = (float4*)sa;
        const int total = FRR * H / 4;   // 1024
        if (r0 + FRR <= Nc) {
            const float4* src = (const float4*)(attr + (size_t)r0 * H);
            for (int i = tid; i < total; i += 256) dst[i] = src[i];
        } else {
            for (int i = tid; i < total; i += 256) {
                int r = i / (H / 4);
                if (r0 + r < Nc) dst[i] = ((const float4*)(attr + (size_t)r0 * H))[i];
                else dst[i] = make_float4(0.0f, 0.0f, 0.0f, 0.0f);
            }
        }
    }
    __syncthreads();

    float acc[8];
#pragma unroll
    for (int r = 0; r < 8; ++r) acc[r] = 0.0f;
    for (int k = 0; k < H; k += 4) {
        float w0 = lin1_w[(k + 0) * F + f];
        float w1 = lin1_w[(k + 1) * F + f];
        float w2 = lin1_w[(k + 2) * F + f];
        float w3 = lin1_w[(k + 3) * F + f];
#pragma unroll
        for (int r = 0; r < 8; ++r) {
            float4 a4 = *(const float4*)&sa[g * 8 + r][k];
            acc[r] = fmaf(a4.x, w0, acc[r]);
            acc[r] = fmaf(a4.y, w1, acc[r]);
            acc[r] = fmaf(a4.z, w2, acc[r]);
            acc[r] = fmaf(a4.w, w3, acc[r]);
        }
    }
#pragma unroll
    for (int r = 0; r < 8; ++r) {
        int row = r0 + g * 8 + r;
        if (row < Nc) ctx_feat[(size_t)row * F + f] = acc[r];
    }
}

__device__ __forceinline__ void knn_body(char* smem, const float* __restrict__ posq,
                                         const float4* __restrict__ posc4,
                                         const int* __restrict__ bq,
                                         const int* __restrict__ ctx_start,
                                         int* __restrict__ nbr, int Nq,
                                         int blk, int tid) {
    unsigned char (*sbin)[BINCAP] = (unsigned char (*)[BINCAP])(smem);          // 10240
    int (*hist)[KBINS]            = (int (*)[KBINS])(smem + 10240);             // 1024
    unsigned (*bkey)[BCAP]        = (unsigned (*)[BCAP])(smem + 11264);         // 2048
    int (*bidx)[BCAP]             = (int (*)[BCAP])(smem + 13312);              // 2048
    int* s_nwin                   = (int*)(smem + 15360);
    int* s_nbnd                   = (int*)(smem + 15376);

    int lane = tid & 63;
    int w = tid >> 6;
    int q = blk * 4 + w;
    bool active = q < Nq;
    int qc = active ? q : 0;

    hist[w][lane] = 0;
    if (lane == 0) { s_nwin[w] = 0; s_nbnd[w] = 0; }

    float qx = posq[qc * 3 + 0];
    float qy = posq[qc * 3 + 1];
    float qz = posq[qc * 3 + 2];
    int b = bq[qc];
    int c0 = ctx_start[b];
    int c1 = ctx_start[b + 1];
    int seg = active ? (c1 - c0) : 0;
    __syncthreads();

    const float SCALE = (float)KBINS / RCUT2;
    int farc = -1;

    for (int i = lane; i < seg; i += 64) {
        float d2 = d2f4(posc4[c0 + i], qx, qy, qz);
        int bin = 255;
        if (d2 < RCUT2) {
            bin = (int)(d2 * SCALE);
            atomicAdd(&hist[w][bin], 1);
        }
        if (i < BINCAP) sbin[w][i] = (unsigned char)bin;
    }
    __syncthreads();

    int h = hist[w][lane];
    int inc = h;
#pragma unroll
    for (int off = 1; off < 64; off <<= 1) {
        int v = __shfl_up(inc, off);
        if (lane >= off) inc += v;
    }
    unsigned long long bal = __ballot(inc >= K);
    int T, below;
    if (bal) {
        T = __ffsll(bal) - 1;
        below = __shfl(inc, T) - __shfl(h, T);
    } else {
        T = KBINS;
        below = __shfl(inc, 63);
    }

    for (int i = lane; i < seg; i += 64) {
        int c = c0 + i;
        int bin;
        if (i < BINCAP) bin = sbin[w][i];
        else {
            float d2 = d2f4(posc4[c], qx, qy, qz);
            bin = (d2 < RCUT2) ? (int)(d2 * SCALE) : 255;
        }
        if (bin < T) {
            int p = atomicAdd(&s_nwin[w], 1);
            nbr[(size_t)q * K + p] = c;
        } else if (bin == T) {
            int p = atomicAdd(&s_nbnd[w], 1);
            if (p < BCAP) {
                float d2 = d2f4(posc4[c], qx, qy, qz);
                bkey[w][p] = __float_as_uint(d2);
                bidx[w][p] = c;
            }
        } else if (bin == 255) {
            farc = c;
        }
    }
#pragma unroll
    for (int off = 1; off < 64; off <<= 1) farc = max(farc, __shfl_xor(farc, off));
    if (farc < 0) farc = c0;
    __syncthreads();

    if (!active) return;
    int nb = min(s_nbnd[w], BCAP);
    int m = K - s_nwin[w];
    for (int it = 0; it < m; ++it) {
        unsigned bestk = 0xFFFFFFFFu;
        int bestp = -1;
        for (int p = lane; p < nb; p += 64) {
            unsigned kk = bkey[w][p];
            if (kk < bestk) { bestk = kk; bestp = p; }
        }
#pragma unroll
        for (int off = 1; off < 64; off <<= 1) {
            unsigned ok = __shfl_xor(bestk, off);
            int op = __shfl_xor(bestp, off);
            if (ok < bestk) { bestk = ok; bestp = op; }
        }
        if (lane == 0) {
            if (bestk != 0xFFFFFFFFu && bestp >= 0) {
                nbr[(size_t)q * K + below + it] = bidx[w][bestp];
                bkey[w][bestp] = 0xFFFFFFFFu;
            } else {
                nbr[(size_t)q * K + below + it] = farc;
            }
        }
        __asm__ volatile("" ::: "memory");
    }
}

// 17 rows per block (16 output pairs need row t0+16); writes float2 (W[t], W[t+1]) table
__device__ __forceinline__ void wtab_body(char* smem, const float* __restrict__ nn1_w,
                                          const float* __restrict__ nn1_b,
                                          const float* __restrict__ nn2_w,
                                          const float* __restrict__ nn2_b,
                                          float2* __restrict__ wt2,
                                          int blk, int tid) {
    float (*sg)[F] = (float (*)[F])smem;             // 17*512 = 8704
    float (*st)[F] = (float (*)[F])(smem + 8704);    // 8704
    int t0 = blk * FRR;
    int f = tid & (F - 1);
    int g = tid >> 7;

    const float delta = 10.0f / 127.0f;
    const float coeff = -0.5f / (delta * delta);
    float off = (float)f * delta;
    for (int r = g; r < 17; r += 2) {
        float dist = (float)(t0 + r) * (10.0f / (float)TAB);
        float d = dist - off;
        sg[r][f] = expf(coeff * d * d);
    }
    __syncthreads();

    float acc[9];
#pragma unroll
    for (int r = 0; r < 9; ++r) acc[r] = 0.0f;
    for (int j = 0; j < F; j += 4) {
        float w0 = nn1_w[(j + 0) * F + f];
        float w1 = nn1_w[(j + 1) * F + f];
        float w2 = nn1_w[(j + 2) * F + f];
        float w3 = nn1_w[(j + 3) * F + f];
#pragma unroll
        for (int r = 0; r < 9; ++r) {
            float4 a4 = *(const float4*)&sg[g * 8 + r][j];
            acc[r] = fmaf(a4.x, w0, acc[r]);
            acc[r] = fmaf(a4.y, w1, acc[r]);
            acc[r] = fmaf(a4.z, w2, acc[r]);
            acc[r] = fmaf(a4.w, w3, acc[r]);
        }
    }
    float b1 = nn1_b[f];
#pragma unroll
    for (int r = 0; r < 9; ++r) st[g * 8 + r][f] = ssp(acc[r] + b1);
    __syncthreads();

#pragma unroll
    for (int r = 0; r < 9; ++r) acc[r] = 0.0f;
    for (int j = 0; j < F; j += 4) {
        float w0 = nn2_w[(j + 0) * F + f];
        float w1 = nn2_w[(j + 1) * F + f];
        float w2 = nn2_w[(j + 2) * F + f];
        float w3 = nn2_w[(j + 3) * F + f];
#pragma unroll
        for (int r = 0; r < 9; ++r) {
            float4 a4 = *(const float4*)&st[g * 8 + r][j];
            acc[r] = fmaf(a4.x, w0, acc[r]);
            acc[r] = fmaf(a4.y, w1, acc[r]);
            acc[r] = fmaf(a4.z, w2, acc[r]);
            acc[r] = fmaf(a4.w, w3, acc[r]);
        }
    }
    float b2 = nn2_b[f];
#pragma unroll
    for (int i = 0; i < 8; ++i) {
        int t = t0 + g * 8 + i;
        wt2[(size_t)t * F + f] = make_float2(acc[i] + b2, acc[i + 1] + b2);
    }
}

__global__ __launch_bounds__(256) void phase2_kernel(const float* __restrict__ attr,
                                                     const float* __restrict__ lin1_w,
                                                     float* __restrict__ ctx_feat, int Nc,
                                                     const float* __restrict__ posq,
                                                     const float4* __restrict__ posc4,
                                                     const int* __restrict__ bq,
                                                     const int* __restrict__ ctx_start,
                                                     int* __restrict__ nbr, int Nq,
                                                     const float* __restrict__ nn1_w,
                                                     const float* __restrict__ nn1_b,
                                                     const float* __restrict__ nn2_w,
                                                     const float* __restrict__ nn2_b,
                                                     float2* __restrict__ wt2,
                                                     int featB, int knnB) {
    __shared__ __align__(16) char smem[17408];
    int blk = blockIdx.x;
    int tid = threadIdx.x;
    if (blk < featB) {
        feat_body(smem, attr, lin1_w, ctx_feat, Nc, blk, tid);
    } else if (blk < featB + knnB) {
        knn_body(smem, posq, posc4, bq, ctx_start, nbr, Nq, blk - featB, tid);
    } else {
        wtab_body(smem, nn1_w, nn1_b, nn2_w, nn2_b, wt2, blk - featB - knnB, tid);
    }
}

// ================= fused agg + head: 8 queries per 256-thread block =================
__global__ __launch_bounds__(256) void agghead_kernel(const float* __restrict__ posq,
                                                      const float4* __restrict__ posc4,
                                                      const int* __restrict__ nbr,
                                                      const float* __restrict__ ctx_feat,
                                                      const float2* __restrict__ wt2,
                                                      const float* __restrict__ lin2_w,
                                                      const float* __restrict__ lin2_b,
                                                      const float* __restrict__ cls1_w,
                                                      const float* __restrict__ cls1_b,
                                                      const float* __restrict__ cls2_w,
                                                      const float* __restrict__ cls2_b,
                                                      const float* __restrict__ prop1_w,
                                                      const float* __restrict__ prop1_b,
                                                      const float* __restrict__ prop2_w,
                                                      const float* __restrict__ prop2_b,
                                                      float* __restrict__ out_cls,
                                                      float* __restrict__ out_ind, int Nq) {
    const int QH = QB / 2;
    int q0 = blockIdx.x * QB;
    int tid = threadIdx.x;

    __shared__ int   sj[QB * K];
    __shared__ float sC[QB * K];
    __shared__ int   si0[QB * K];
    __shared__ float sfr[QB * K];
    __shared__ float sa[QB][F];
    __shared__ float ssc[QB];
    __shared__ float sy[QB][FP];
    __shared__ float sc1[QB][FP];
    __shared__ float sp1[QB][FP];

    // ---- per-edge stage: one edge per thread (8q x 32k) ----
    {
        int qq = tid >> 5;                 // 0..7
        int q = q0 + qq;
        if (q >= Nq) q = Nq - 1;           // clamp; stores guarded later
        int j = nbr[(size_t)q * K + (tid & 31)];
        float4 p = posc4[j];
        float dx = posq[q * 3 + 0] - p.x;
        float dy = posq[q * 3 + 1] - p.y;
        float dz = posq[q * 3 + 2] - p.z;
        float dist = sqrtf(fmaf(dz, dz, fmaf(dy, dy, dx * dx)));
        float C = 0.0f, fr = 0.0f;
        int i0 = 0;
        if (dist <= 10.0f) {
            C = 0.5f * (cosf(dist * 0.31415926535897931f) + 1.0f);
            float u = dist * ((float)TAB / 10.0f);
            i0 = (int)u;
            if (i0 > TAB - 1) i0 = TAB - 1;
            fr = u - (float)i0;
        }
        sj[tid] = j; sC[tid] = C; si0[tid] = i0; sfr[tid] = fr;
        // csum over the 32-lane group (xor offsets <32 stay in-group)
        float cs = C;
#pragma unroll
        for (int off = 1; off < 32; off <<= 1) cs += __shfl_xor(cs, off);
        if ((tid & 31) == 0) ssc[qq] = cs;
    }
    __syncthreads();

    int f = tid & (F - 1);
    int g = tid >> 7;

    // ---- agg: acc_f = sum_k C*(lerp(wt2)) * ctx_feat ; 4 queries per thread ----
    {
        float acc[QH] = {0.0f, 0.0f, 0.0f, 0.0f};
#pragma unroll 2
        for (int k = 0; k < K; ++k) {
#pragma unroll
            for (int i = 0; i < QH; ++i) {
                int e = (g * QH + i) * K + k;
                int j = sj[e];
                float C = sC[e];
                int i0 = si0[e];
                float fr = sfr[e];
                float2 w = wt2[(size_t)i0 * F + f];
                float a = ctx_feat[(size_t)j * F + f];
                float W = fmaf(fr, w.y - w.x, w.x);
                acc[i] = fmaf(C * W, a, acc[i]);
            }
        }
#pragma unroll
        for (int i = 0; i < QH; ++i) sa[g * QH + i][f] = acc[i];
    }
    __syncthreads();

    // ---- head stage A: y = sa @ lin2_w + ssc*lin2_b ----
    {
        float y[QH];
        float lb = lin2_b[f];
#pragma unroll
        for (int i = 0; i < QH; ++i) y[i] = ssc[g * QH + i] * lb;
        for (int j = 0; j < F; j += 4) {
            float w0 = lin2_w[(j + 0) * F + f];
            float w1 = lin2_w[(j + 1) * F + f];
            float w2 = lin2_w[(j + 2) * F + f];
            float w3 = lin2_w[(j + 3) * F + f];
#pragma unroll
            for (int i = 0; i < QH; ++i) {
                float4 a4 = *(const float4*)&sa[g * QH + i][j];
                y[i] = fmaf(a4.x, w0, y[i]);
                y[i] = fmaf(a4.y, w1, y[i]);
                y[i] = fmaf(a4.z, w2, y[i]);
                y[i] = fmaf(a4.w, w3, y[i]);
            }
        }
#pragma unroll
        for (int i = 0; i < QH; ++i) sy[g * QH + i][f] = y[i];
    }
    __syncthreads();

    // ---- head stage B: c1 = ssp(y@cls1+b), p1 = ssp(y@prop1+b) ----
    {
        float c1[QH], p1[QH];
        float cb = cls1_b[f], pb = prop1_b[f];
#pragma unroll
        for (int i = 0; i < QH; ++i) { c1[i] = cb; p1[i] = pb; }
        for (int j = 0; j < F; j += 4) {
            float wc0 = cls1_w[(j + 0) * F + f];
            float wc1 = cls1_w[(j + 1) * F + f];
            float wc2 = cls1_w[(j + 2) * F + f];
            float wc3 = cls1_w[(j + 3) * F + f];
            float wp0 = prop1_w[(j + 0) * F + f];
            float wp1 = prop1_w[(j + 1) * F + f];
            float wp2 = prop1_w[(j + 2) * F + f];
            float wp3 = prop1_w[(j + 3) * F + f];
#pragma unroll
            for (int i = 0; i < QH; ++i) {
                float4 y4 = *(const float4*)&sy[g * QH + i][j];
                c1[i] = fmaf(y4.x, wc0, c1[i]);
                c1[i] = fmaf(y4.y, wc1, c1[i]);
                c1[i] = fmaf(y4.z, wc2, c1[i]);
                c1[i] = fmaf(y4.w, wc3, c1[i]);
                p1[i] = fmaf(y4.x, wp0, p1[i]);
                p1[i] = fmaf(y4.y, wp1, p1[i]);
                p1[i] = fmaf(y4.z, wp2, p1[i]);
                p1[i] = fmaf(y4.w, wp3, p1[i]);
            }
        }
#pragma unroll
        for (int i = 0; i < QH; ++i) {
            sc1[g * QH + i][f] = ssp(c1[i]);
            sp1[g * QH + i][f] = ssp(p1[i]);
        }
    }
    __syncthreads();

    // ---- tails: 8 queries x 15 outputs ----
    {
        int qq = tid >> 5;
        int c = tid & 31;
        int q = q0 + qq;
        if (q < Nq && c < 15) {
            if (c < 7) {
                float acc = cls2_b[c];
                for (int j = 0; j < F; ++j) acc = fmaf(sc1[qq][j], cls2_w[j * 7 + c], acc);
                out_cls[(size_t)q * 7 + c] = acc;
            } else {
                int cc = c - 7;
                float acc = prop2_b[cc];
                for (int j = 0; j < F; ++j) acc = fmaf(sp1[qq][j], prop2_w[j * 8 + cc], acc);
                out_ind[(size_t)q * 8 + cc] = acc;
            }
        }
    }
}

extern "C" void kernel_launch(void* const* d_in, const int* in_sizes, int n_in,
                              void* d_out, int out_size, void* d_ws, size_t ws_size,
                              hipStream_t stream) {
    const float* posq   = (const float*)d_in[0];
    const float* posc   = (const float*)d_in[1];
    const float* attr   = (const float*)d_in[2];
    const int*   bq     = (const int*)d_in[3];
    const int*   bc     = (const int*)d_in[4];
    const float* lin1_w = (const float*)d_in[5];
    const float* lin2_w = (const float*)d_in[6];
    const float* lin2_b = (const float*)d_in[7];
    const float* nn1_w  = (const float*)d_in[8];
    const float* nn1_b  = (const float*)d_in[9];
    const float* nn2_w  = (const float*)d_in[10];
    const float* nn2_b  = (const float*)d_in[11];
    const float* cls1_w = (const float*)d_in[12];
    const float* cls1_b = (const float*)d_in[13];
    const float* cls2_w = (const float*)d_in[14];
    const float* cls2_b = (const float*)d_in[15];
    const float* prop1_w = (const float*)d_in[16];
    const float* prop1_b = (const float*)d_in[17];
    const float* prop2_w = (const float*)d_in[18];
    const float* prop2_b = (const float*)d_in[19];
    (void)n_in; (void)out_size; (void)ws_size;

    int Nq = in_sizes[0] / 3;
    int Nc = in_sizes[1] / 3;

    char* ws = (char*)d_ws;
    size_t off = 0;
    auto alloc = [&](size_t bytes) {
        off = (off + 255) & ~(size_t)255;
        void* p = ws + off;
        off += bytes;
        return p;
    };
    int*    ctx_start = (int*)alloc((BMAX + 1) * sizeof(int));
    int*    nbr       = (int*)alloc((size_t)Nq * K * sizeof(int));
    float*  ctx_feat  = (float*)alloc((size_t)Nc * F * sizeof(float));
    float2* wt2       = (float2*)alloc((size_t)TAB * F * sizeof(float2));
    float4* posc4     = (float4*)alloc((size_t)Nc * sizeof(float4));

    float* out_cls = (float*)d_out;
    float* out_ind = out_cls + (size_t)Nq * 7;

    int padB  = (Nc + 255) / 256;
    int featB = (Nc + FRR - 1) / FRR;       // 1024
    int knnB  = (Nq + 3) / 4;               // 2048
    int wtabB = TAB / FRR;                  // 256

    prep_kernel<<<dim3(1 + padB), dim3(256), 0, stream>>>(bc, Nc, ctx_start, posc, posc4);
    phase2_kernel<<<dim3(featB + knnB + wtabB), dim3(256), 0, stream>>>(
        attr, lin1_w, ctx_feat, Nc,
        posq, posc4, bq, ctx_start, nbr, Nq,
        nn1_w, nn1_b, nn2_w, nn2_b, wt2, featB, knnB);
    agghead_kernel<<<dim3((Nq + QB - 1) / QB), dim3(256), 0, stream>>>(
        posq, posc4, nbr, ctx_feat, wt2,
        lin2_w, lin2_b, cls1_w, cls1_b, cls2_w, cls2_b,
        prop1_w, prop1_b, prop2_w, prop2_b, out_cls, out_ind, Nq);
}

// Round 9
// 133.728 us; speedup vs baseline: 1.7929x; 1.0762x over previous
//
#include <hip/hip_runtime.h>
#include <math.h>

#define K 32
#define F 128
#define H 256
#define TAB 4096
#define QB 8
#define BMAX 16
#define RCUT2 100.0f
#define KBINS 64
#define BINCAP 2560
#define BCAP 128
#define FP 132   // padded LDS row stride
#define FRR 16   // rows per block in feat/wtab GEMMs

__device__ __forceinline__ float ssp(float x) {
    return fmaxf(x, 0.0f) + log1pf(expf(-fabsf(x))) - 0.69314718055994531f;
}

__device__ __forceinline__ float d2f4(float4 p, float qx, float qy, float qz) {
    float dx = qx - p.x;
    float dy = qy - p.y;
    float dz = qz - p.z;
    return fmaf(dz, dz, fmaf(dy, dy, dx * dx));
}

// ---------------- prep: seg boundaries + pos padding ----------------
__global__ __launch_bounds__(256) void prep_kernel(const int* __restrict__ bc, int Nc,
                                                   int* __restrict__ ctx_start,
                                                   const float* __restrict__ posc,
                                                   float4* __restrict__ posc4) {
    int blk = blockIdx.x;
    int tid = threadIdx.x;
    if (blk == 0) {
        if (tid <= BMAX) {
            int b = tid;
            int lo = 0, hi = Nc;
            while (lo < hi) {
                int mid = (lo + hi) >> 1;
                if (bc[mid] < b) lo = mid + 1; else hi = mid;
            }
            ctx_start[b] = lo;
        }
    } else {
        int i = (blk - 1) * 256 + tid;
        if (i < Nc)
            posc4[i] = make_float4(posc[i * 3 + 0], posc[i * 3 + 1], posc[i * 3 + 2], 0.0f);
    }
}

// ================= phase2 bodies (share one LDS union) =================

// 4 rows x 2 cols per thread: per 4-k step = 4 ds_read_b128 + 8 coalesced w loads + 32 FMA
__device__ __forceinline__ void feat_body(char* smem, const float* __restrict__ attr,
                                          const float* __restrict__ lin1_w,
                                          float* __restrict__ ctx_feat, int Nc,
                                          int blk, int tid) {
    float (*sa)[H] = (float (*)[H])smem;   // 16 KB
    int r0 = blk * FRR;
    int f = tid & 63;        // cols f and f+64
    int g = tid >> 6;        // row group: rows g*4 .. g*4+3

    {
        float4* dst = (float4*)sa;
        const int total = FRR * H / 4;   // 1024
        if (r0 + FRR <= Nc) {
            const float4* src = (const float4*)(attr + (size_t)r0 * H);
            for (int i = tid; i < total; i += 256) dst[i] = src[i];
        } else {
            for (int i = tid; i < total; i += 256) {
                int r = i / (H / 4);
                if (r0 + r < Nc) dst[i] = ((const float4*)(attr + (size_t)r0 * H))[i];
                else dst[i] = make_float4(0.0f, 0.0f, 0.0f, 0.0f);
            }
        }
    }
    __syncthreads();

    float acc0[4], acc1[4];
#pragma unroll
    for (int r = 0; r < 4; ++r) { acc0[r] = 0.0f; acc1[r] = 0.0f; }
    for (int k = 0; k < H; k += 4) {
        float wa0 = lin1_w[(k + 0) * F + f];
        float wa1 = lin1_w[(k + 1) * F + f];
        float wa2 = lin1_w[(k + 2) * F + f];
        float wa3 = lin1_w[(k + 3) * F + f];
        float wb0 = lin1_w[(k + 0) * F + f + 64];
        float wb1 = lin1_w[(k + 1) * F + f + 64];
        float wb2 = lin1_w[(k + 2) * F + f + 64];
        float wb3 = lin1_w[(k + 3) * F + f + 64];
#pragma unroll
        for (int r = 0; r < 4; ++r) {
            float4 a4 = *(const float4*)&sa[g * 4 + r][k];   // wave-uniform -> broadcast
            acc0[r] = fmaf(a4.x, wa0, acc0[r]);
            acc0[r] = fmaf(a4.y, wa1, acc0[r]);
            acc0[r] = fmaf(a4.z, wa2, acc0[r]);
            acc0[r] = fmaf(a4.w, wa3, acc0[r]);
            acc1[r] = fmaf(a4.x, wb0, acc1[r]);
            acc1[r] = fmaf(a4.y, wb1, acc1[r]);
            acc1[r] = fmaf(a4.z, wb2, acc1[r]);
            acc1[r] = fmaf(a4.w, wb3, acc1[r]);
        }
    }
#pragma unroll
    for (int r = 0; r < 4; ++r) {
        int row = r0 + g * 4 + r;
        if (row < Nc) {
            ctx_feat[(size_t)row * F + f] = acc0[r];
            ctx_feat[(size_t)row * F + f + 64] = acc1[r];
        }
    }
}

__device__ __forceinline__ void knn_body(char* smem, const float* __restrict__ posq,
                                         const float4* __restrict__ posc4,
                                         const int* __restrict__ bq,
                                         const int* __restrict__ ctx_start,
                                         int* __restrict__ nbr, int Nq,
                                         int blk, int tid) {
    unsigned char (*sbin)[BINCAP] = (unsigned char (*)[BINCAP])(smem);          // 10240
    int (*hist)[KBINS]            = (int (*)[KBINS])(smem + 10240);             // 1024
    unsigned (*bkey)[BCAP]        = (unsigned (*)[BCAP])(smem + 11264);         // 2048
    int (*bidx)[BCAP]             = (int (*)[BCAP])(smem + 13312);              // 2048
    int* s_nwin                   = (int*)(smem + 15360);
    int* s_nbnd                   = (int*)(smem + 15376);

    int lane = tid & 63;
    int w = tid >> 6;
    int q = blk * 4 + w;
    bool active = q < Nq;
    int qc = active ? q : 0;

    hist[w][lane] = 0;
    if (lane == 0) { s_nwin[w] = 0; s_nbnd[w] = 0; }

    float qx = posq[qc * 3 + 0];
    float qy = posq[qc * 3 + 1];
    float qz = posq[qc * 3 + 2];
    int b = bq[qc];
    int c0 = ctx_start[b];
    int c1 = ctx_start[b + 1];
    int seg = active ? (c1 - c0) : 0;
    __syncthreads();

    const float SCALE = (float)KBINS / RCUT2;
    int farc = -1;

    for (int i = lane; i < seg; i += 64) {
        float d2 = d2f4(posc4[c0 + i], qx, qy, qz);
        int bin = 255;
        if (d2 < RCUT2) {
            bin = (int)(d2 * SCALE);
            atomicAdd(&hist[w][bin], 1);
        }
        if (i < BINCAP) sbin[w][i] = (unsigned char)bin;
    }
    __syncthreads();

    int h = hist[w][lane];
    int inc = h;
#pragma unroll
    for (int off = 1; off < 64; off <<= 1) {
        int v = __shfl_up(inc, off);
        if (lane >= off) inc += v;
    }
    unsigned long long bal = __ballot(inc >= K);
    int T, below;
    if (bal) {
        T = __ffsll(bal) - 1;
        below = __shfl(inc, T) - __shfl(h, T);
    } else {
        T = KBINS;
        below = __shfl(inc, 63);
    }

    for (int i = lane; i < seg; i += 64) {
        int c = c0 + i;
        int bin;
        if (i < BINCAP) bin = sbin[w][i];
        else {
            float d2 = d2f4(posc4[c], qx, qy, qz);
            bin = (d2 < RCUT2) ? (int)(d2 * SCALE) : 255;
        }
        if (bin < T) {
            int p = atomicAdd(&s_nwin[w], 1);
            nbr[(size_t)q * K + p] = c;
        } else if (bin == T) {
            int p = atomicAdd(&s_nbnd[w], 1);
            if (p < BCAP) {
                float d2 = d2f4(posc4[c], qx, qy, qz);
                bkey[w][p] = __float_as_uint(d2);
                bidx[w][p] = c;
            }
        } else if (bin == 255) {
            farc = c;
        }
    }
#pragma unroll
    for (int off = 1; off < 64; off <<= 1) farc = max(farc, __shfl_xor(farc, off));
    if (farc < 0) farc = c0;
    __syncthreads();

    if (!active) return;
    int nb = min(s_nbnd[w], BCAP);
    int m = K - s_nwin[w];
    // pick m smallest by (d2, ctx_index): deterministic under atomic reordering,
    // and matches jax top_k's stable lowest-index tie-break.
    for (int it = 0; it < m; ++it) {
        unsigned long long bestkey = 0xFFFFFFFFFFFFFFFFull;
        int bestp = -1;
        for (int p = lane; p < nb; p += 64) {
            unsigned kk = bkey[w][p];
            if (kk != 0xFFFFFFFFu) {
                unsigned long long pk = ((unsigned long long)kk << 32) | (unsigned)bidx[w][p];
                if (pk < bestkey) { bestkey = pk; bestp = p; }
            }
        }
#pragma unroll
        for (int off = 1; off < 64; off <<= 1) {
            unsigned long long ok = __shfl_xor(bestkey, off);
            int op = __shfl_xor(bestp, off);
            if (ok < bestkey) { bestkey = ok; bestp = op; }
        }
        if (lane == 0) {
            if (bestp >= 0 && bestkey != 0xFFFFFFFFFFFFFFFFull) {
                nbr[(size_t)q * K + below + it] = (int)(bestkey & 0xFFFFFFFFu);
                bkey[w][bestp] = 0xFFFFFFFFu;
            } else {
                nbr[(size_t)q * K + below + it] = farc;   // pad: contributes 0
            }
        }
        __asm__ volatile("" ::: "memory");
    }
}

// 17 rows per block (16 output pairs need row t0+16); writes float2 (W[t], W[t+1]) table
__device__ __forceinline__ void wtab_body(char* smem, const float* __restrict__ nn1_w,
                                          const float* __restrict__ nn1_b,
                                          const float* __restrict__ nn2_w,
                                          const float* __restrict__ nn2_b,
                                          float2* __restrict__ wt2,
                                          int blk, int tid) {
    float (*sg)[F] = (float (*)[F])smem;             // 17*512 = 8704
    float (*st)[F] = (float (*)[F])(smem + 8704);    // 8704
    int t0 = blk * FRR;
    int f = tid & (F - 1);
    int g = tid >> 7;

    const float delta = 10.0f / 127.0f;
    const float coeff = -0.5f / (delta * delta);
    float off = (float)f * delta;
    for (int r = g; r < 17; r += 2) {
        float dist = (float)(t0 + r) * (10.0f / (float)TAB);
        float d = dist - off;
        sg[r][f] = expf(coeff * d * d);
    }
    __syncthreads();

    float acc[9];
#pragma unroll
    for (int r = 0; r < 9; ++r) acc[r] = 0.0f;
    for (int j = 0; j < F; j += 4) {
        float w0 = nn1_w[(j + 0) * F + f];
        float w1 = nn1_w[(j + 1) * F + f];
        float w2 = nn1_w[(j + 2) * F + f];
        float w3 = nn1_w[(j + 3) * F + f];
#pragma unroll
        for (int r = 0; r < 9; ++r) {
            float4 a4 = *(const float4*)&sg[g * 8 + r][j];
            acc[r] = fmaf(a4.x, w0, acc[r]);
            acc[r] = fmaf(a4.y, w1, acc[r]);
            acc[r] = fmaf(a4.z, w2, acc[r]);
            acc[r] = fmaf(a4.w, w3, acc[r]);
        }
    }
    float b1 = nn1_b[f];
#pragma unroll
    for (int r = 0; r < 9; ++r) st[g * 8 + r][f] = ssp(acc[r] + b1);
    __syncthreads();

#pragma unroll
    for (int r = 0; r < 9; ++r) acc[r] = 0.0f;
    for (int j = 0; j < F; j += 4) {
        float w0 = nn2_w[(j + 0) * F + f];
        float w1 = nn2_w[(j + 1) * F + f];
        float w2 = nn2_w[(j + 2) * F + f];
        float w3 = nn2_w[(j + 3) * F + f];
#pragma unroll
        for (int r = 0; r < 9; ++r) {
            float4 a4 = *(const float4*)&st[g * 8 + r][j];
            acc[r] = fmaf(a4.x, w0, acc[r]);
            acc[r] = fmaf(a4.y, w1, acc[r]);
            acc[r] = fmaf(a4.z, w2, acc[r]);
            acc[r] = fmaf(a4.w, w3, acc[r]);
        }
    }
    float b2 = nn2_b[f];
#pragma unroll
    for (int i = 0; i < 8; ++i) {
        int t = t0 + g * 8 + i;
        wt2[(size_t)t * F + f] = make_float2(acc[i] + b2, acc[i + 1] + b2);
    }
}

// partition order: knn (latency-bound, fills machine first), wtab, feat
__global__ __launch_bounds__(256) void phase2_kernel(const float* __restrict__ attr,
                                                     const float* __restrict__ lin1_w,
                                                     float* __restrict__ ctx_feat, int Nc,
                                                     const float* __restrict__ posq,
                                                     const float4* __restrict__ posc4,
                                                     const int* __restrict__ bq,
                                                     const int* __restrict__ ctx_start,
                                                     int* __restrict__ nbr, int Nq,
                                                     const float* __restrict__ nn1_w,
                                                     const float* __restrict__ nn1_b,
                                                     const float* __restrict__ nn2_w,
                                                     const float* __restrict__ nn2_b,
                                                     float2* __restrict__ wt2,
                                                     int knnB, int wtabB) {
    __shared__ __align__(16) char smem[17408];
    int blk = blockIdx.x;
    int tid = threadIdx.x;
    if (blk < knnB) {
        knn_body(smem, posq, posc4, bq, ctx_start, nbr, Nq, blk, tid);
    } else if (blk < knnB + wtabB) {
        wtab_body(smem, nn1_w, nn1_b, nn2_w, nn2_b, wt2, blk - knnB, tid);
    } else {
        feat_body(smem, attr, lin1_w, ctx_feat, Nc, blk - knnB - wtabB, tid);
    }
}

// ================= fused agg + head: 8 queries per 256-thread block =================
__global__ __launch_bounds__(256) void agghead_kernel(const float* __restrict__ posq,
                                                      const float4* __restrict__ posc4,
                                                      const int* __restrict__ nbr,
                                                      const float* __restrict__ ctx_feat,
                                                      const float2* __restrict__ wt2,
                                                      const float* __restrict__ lin2_w,
                                                      const float* __restrict__ lin2_b,
                                                      const float* __restrict__ cls1_w,
                                                      const float* __restrict__ cls1_b,
                                                      const float* __restrict__ cls2_w,
                                                      const float* __restrict__ cls2_b,
                                                      const float* __restrict__ prop1_w,
                                                      const float* __restrict__ prop1_b,
                                                      const float* __restrict__ prop2_w,
                                                      const float* __restrict__ prop2_b,
                                                      float* __restrict__ out_cls,
                                                      float* __restrict__ out_ind, int Nq) {
    const int QH = QB / 2;
    int q0 = blockIdx.x * QB;
    int tid = threadIdx.x;

    __shared__ int   sj[QB * K];
    __shared__ float sC[QB * K];
    __shared__ int   si0[QB * K];
    __shared__ float sfr[QB * K];
    __shared__ float sa[QB][F];
    __shared__ float ssc[QB];
    __shared__ float sy[QB][FP];
    __shared__ float sc1[QB][FP];
    __shared__ float sp1[QB][FP];

    // ---- per-edge stage: one edge per thread (8q x 32k) ----
    {
        int qq = tid >> 5;
        int q = q0 + qq;
        if (q >= Nq) q = Nq - 1;
        int j = nbr[(size_t)q * K + (tid & 31)];
        float4 p = posc4[j];
        float dx = posq[q * 3 + 0] - p.x;
        float dy = posq[q * 3 + 1] - p.y;
        float dz = posq[q * 3 + 2] - p.z;
        float dist = sqrtf(fmaf(dz, dz, fmaf(dy, dy, dx * dx)));
        float C = 0.0f, fr = 0.0f;
        int i0 = 0;
        if (dist <= 10.0f) {
            C = 0.5f * (cosf(dist * 0.31415926535897931f) + 1.0f);
            float u = dist * ((float)TAB / 10.0f);
            i0 = (int)u;
            if (i0 > TAB - 1) i0 = TAB - 1;
            fr = u - (float)i0;
        }
        sj[tid] = j; sC[tid] = C; si0[tid] = i0; sfr[tid] = fr;
        float cs = C;
#pragma unroll
        for (int off = 1; off < 32; off <<= 1) cs += __shfl_xor(cs, off);
        if ((tid & 31) == 0) ssc[qq] = cs;
    }
    __syncthreads();

    int f = tid & (F - 1);
    int g = tid >> 7;

    // ---- agg: acc_f = sum_k C*(lerp(wt2)) * ctx_feat ; 4 queries per thread ----
    {
        float acc[QH] = {0.0f, 0.0f, 0.0f, 0.0f};
#pragma unroll 2
        for (int k = 0; k < K; ++k) {
#pragma unroll
            for (int i = 0; i < QH; ++i) {
                int e = (g * QH + i) * K + k;
                int j = sj[e];
                float C = sC[e];
                int i0 = si0[e];
                float fr = sfr[e];
                float2 w = wt2[(size_t)i0 * F + f];
                float a = ctx_feat[(size_t)j * F + f];
                float W = fmaf(fr, w.y - w.x, w.x);
                acc[i] = fmaf(C * W, a, acc[i]);
            }
        }
#pragma unroll
        for (int i = 0; i < QH; ++i) sa[g * QH + i][f] = acc[i];
    }
    __syncthreads();

    // ---- head stage A: y = sa @ lin2_w + ssc*lin2_b ----
    {
        float y[QH];
        float lb = lin2_b[f];
#pragma unroll
        for (int i = 0; i < QH; ++i) y[i] = ssc[g * QH + i] * lb;
        for (int j = 0; j < F; j += 4) {
            float w0 = lin2_w[(j + 0) * F + f];
            float w1 = lin2_w[(j + 1) * F + f];
            float w2 = lin2_w[(j + 2) * F + f];
            float w3 = lin2_w[(j + 3) * F + f];
#pragma unroll
            for (int i = 0; i < QH; ++i) {
                float4 a4 = *(const float4*)&sa[g * QH + i][j];
                y[i] = fmaf(a4.x, w0, y[i]);
                y[i] = fmaf(a4.y, w1, y[i]);
                y[i] = fmaf(a4.z, w2, y[i]);
                y[i] = fmaf(a4.w, w3, y[i]);
            }
        }
#pragma unroll
        for (int i = 0; i < QH; ++i) sy[g * QH + i][f] = y[i];
    }
    __syncthreads();

    // ---- head stage B: c1 = ssp(y@cls1+b), p1 = ssp(y@prop1+b) ----
    {
        float c1[QH], p1[QH];
        float cb = cls1_b[f], pb = prop1_b[f];
#pragma unroll
        for (int i = 0; i < QH; ++i) { c1[i] = cb; p1[i] = pb; }
        for (int j = 0; j < F; j += 4) {
            float wc0 = cls1_w[(j + 0) * F + f];
            float wc1 = cls1_w[(j + 1) * F + f];
            float wc2 = cls1_w[(j + 2) * F + f];
            float wc3 = cls1_w[(j + 3) * F + f];
            float wp0 = prop1_w[(j + 0) * F + f];
            float wp1 = prop1_w[(j + 1) * F + f];
            float wp2 = prop1_w[(j + 2) * F + f];
            float wp3 = prop1_w[(j + 3) * F + f];
#pragma unroll
            for (int i = 0; i < QH; ++i) {
                float4 y4 = *(const float4*)&sy[g * QH + i][j];
                c1[i] = fmaf(y4.x, wc0, c1[i]);
                c1[i] = fmaf(y4.y, wc1, c1[i]);
                c1[i] = fmaf(y4.z, wc2, c1[i]);
                c1[i] = fmaf(y4.w, wc3, c1[i]);
                p1[i] = fmaf(y4.x, wp0, p1[i]);
                p1[i] = fmaf(y4.y, wp1, p1[i]);
                p1[i] = fmaf(y4.z, wp2, p1[i]);
                p1[i] = fmaf(y4.w, wp3, p1[i]);
            }
        }
#pragma unroll
        for (int i = 0; i < QH; ++i) {
            sc1[g * QH + i][f] = ssp(c1[i]);
            sp1[g * QH + i][f] = ssp(p1[i]);
        }
    }
    __syncthreads();

    // ---- tails: 8 queries x 15 outputs ----
    {
        int qq = tid >> 5;
        int c = tid & 31;
        int q = q0 + qq;
        if (q < Nq && c < 15) {
            if (c < 7) {
                float acc = cls2_b[c];
                for (int j = 0; j < F; ++j) acc = fmaf(sc1[qq][j], cls2_w[j * 7 + c], acc);
                out_cls[(size_t)q * 7 + c] = acc;
            } else {
                int cc = c - 7;
                float acc = prop2_b[cc];
                for (int j = 0; j < F; ++j) acc = fmaf(sp1[qq][j], prop2_w[j * 8 + cc], acc);
                out_ind[(size_t)q * 8 + cc] = acc;
            }
        }
    }
}

extern "C" void kernel_launch(void* const* d_in, const int* in_sizes, int n_in,
                              void* d_out, int out_size, void* d_ws, size_t ws_size,
                              hipStream_t stream) {
    const float* posq   = (const float*)d_in[0];
    const float* posc   = (const float*)d_in[1];
    const float* attr   = (const float*)d_in[2];
    const int*   bq     = (const int*)d_in[3];
    const int*   bc     = (const int*)d_in[4];
    const float* lin1_w = (const float*)d_in[5];
    const float* lin2_w = (const float*)d_in[6];
    const float* lin2_b = (const float*)d_in[7];
    const float* nn1_w  = (const float*)d_in[8];
    const float* nn1_b  = (const float*)d_in[9];
    const float* nn2_w  = (const float*)d_in[10];
    const float* nn2_b  = (const float*)d_in[11];
    const float* cls1_w = (const float*)d_in[12];
    const float* cls1_b = (const float*)d_in[13];
    const float* cls2_w = (const float*)d_in[14];
    const float* cls2_b = (const float*)d_in[15];
    const float* prop1_w = (const float*)d_in[16];
    const float* prop1_b = (const float*)d_in[17];
    const float* prop2_w = (const float*)d_in[18];
    const float* prop2_b = (const float*)d_in[19];
    (void)n_in; (void)out_size; (void)ws_size;

    int Nq = in_sizes[0] / 3;
    int Nc = in_sizes[1] / 3;

    char* ws = (char*)d_ws;
    size_t off = 0;
    auto alloc = [&](size_t bytes) {
        off = (off + 255) & ~(size_t)255;
        void* p = ws + off;
        off += bytes;
        return p;
    };
    int*    ctx_start = (int*)alloc((BMAX + 1) * sizeof(int));
    int*    nbr       = (int*)alloc((size_t)Nq * K * sizeof(int));
    float*  ctx_feat  = (float*)alloc((size_t)Nc * F * sizeof(float));
    float2* wt2       = (float2*)alloc((size_t)TAB * F * sizeof(float2));
    float4* posc4     = (float4*)alloc((size_t)Nc * sizeof(float4));

    float* out_cls = (float*)d_out;
    float* out_ind = out_cls + (size_t)Nq * 7;

    int padB  = (Nc + 255) / 256;
    int featB = (Nc + FRR - 1) / FRR;       // 1024
    int knnB  = (Nq + 3) / 4;               // 2048
    int wtabB = TAB / FRR;                  // 256

    prep_kernel<<<dim3(1 + padB), dim3(256), 0, stream>>>(bc, Nc, ctx_start, posc, posc4);
    phase2_kernel<<<dim3(knnB + wtabB + featB), dim3(256), 0, stream>>>(
        attr, lin1_w, ctx_feat, Nc,
        posq, posc4, bq, ctx_start, nbr, Nq,
        nn1_w, nn1_b, nn2_w, nn2_b, wt2, knnB, wtabB);
    agghead_kernel<<<dim3((Nq + QB - 1) / QB), dim3(256), 0, stream>>>(
        posq, posc4, nbr, ctx_feat, wt2,
        lin2_w, lin2_b, cls1_w, cls1_b, cls2_w, cls2_b,
        prop1_w, prop1_b, prop2_w, prop2_b, out_cls, out_ind, Nq);
}